// Round 5
// baseline (270.516 us; speedup 1.0000x reference)
//
#include <hip/hip_runtime.h>
#include <math.h>

#define B_GRAPHS 16384
#define N_NODES  524288
#define E_EDGES  1048576
#define D_EMB    128
#define D_STATE  64
#define HID      32
#define PADK     136     // bf16 elems/row -> 272B row stride (16B aligned)
#define WPB      4       // waves per block; each wave owns one 32-node window

typedef __attribute__((ext_vector_type(8))) short short8;
typedef __attribute__((ext_vector_type(4))) float f32x4;

__device__ __forceinline__ unsigned short f2bf(float f) {
    unsigned int u = __builtin_bit_cast(unsigned int, f);
    u += 0x7fffu + ((u >> 16) & 1u);
    return (unsigned short)(u >> 16);
}
__device__ __forceinline__ float bf2f(unsigned short s) {
    unsigned int u = ((unsigned int)s) << 16;
    return __builtin_bit_cast(float, u);
}

// ---------- K0: zero accumulator half of out_x rows + S (replay-safe) ----------
__global__ __launch_bounds__(256) void zero_kernel(float4* __restrict__ out4,
                                                   float4* __restrict__ S4)
{
    int i = blockIdx.x * 256 + threadIdx.x;          // B*32 threads
    int g = i >> 5, q = i & 31;
    out4[(size_t)g * 64 + 32 + q] = make_float4(0.f, 0.f, 0.f, 0.f);
    if (i < B_GRAPHS / 4) S4[i] = make_float4(0.f, 0.f, 0.f, 0.f);
}

// ---------- K1: hb[g][j] = b1[j] + state_emb[state[g]] @ W1[128:192,:] ----------
__global__ __launch_bounds__(256) void hb_kernel(
    const float* __restrict__ state_emb, const float* __restrict__ W1,
    const float* __restrict__ b1, const int* __restrict__ state,
    float* __restrict__ hb)
{
    int t = threadIdx.x;
    int j = t & 31;
    int g = blockIdx.x * 8 + (t >> 5);
    int st = state[g];
    const float* zs = state_emb + st * D_STATE;
    float acc = b1[j];
    #pragma unroll 8
    for (int k = 0; k < D_STATE; ++k)
        acc += zs[k] * W1[(D_EMB + k) * HID + j];
    hb[g * HID + j] = acc;
}

// ---------- K2: node-centric fused logits + exp + segment-flush pooling ----------
__global__ __launch_bounds__(256, 3) void graph_kernel(
    const float* __restrict__ z_atom,
    const float* __restrict__ W1,
    const float* __restrict__ W2,
    const float* __restrict__ b2,
    const int*   __restrict__ batch,
    const float* __restrict__ hb,
    float*       __restrict__ out_x,   // atomic accumulate into [g*256+128 .. +255]
    float*       __restrict__ S)       // atomic accumulate exp-sums
{
    __shared__ unsigned short s_w1t[HID][PADK];     // W1[0:128,:]^T bf16 [j][k]
    __shared__ unsigned short s_zb[WPB][32][PADK];  // per-wave z window bf16 [n][k]

    const int t    = threadIdx.x;
    const int lane = t & 63;
    const int w    = t >> 6;
    const int l15  = lane & 15;
    const int kc   = lane >> 4;        // 0..3

    // stage W1T once per block (W1 row-major [k][j], k<128)
    for (int i = t; i < D_EMB * HID; i += 256) {
        int k = i >> 5, j = i & 31;
        s_w1t[j][k] = f2bf(W1[i]);
    }
    __syncthreads();   // only block-wide barrier

    const float b2v = b2[0];
    float w2v[2][4];
    #pragma unroll
    for (int jh = 0; jh < 2; ++jh)
        #pragma unroll
        for (int r = 0; r < 4; ++r)
            w2v[jh][r] = W2[16 * jh + 4 * kc + r];

    unsigned short (*zb)[PADK] = s_zb[w];

    const int c0 = (blockIdx.x * WPB + w) * 32;     // dense window: 32 valid nodes
    int bv = 0;
    if (lane < 32) bv = batch[c0 + lane];

    // ---- phase A: issue ALL window loads into registers (no per-iter waits) ----
    float4 tmp[16];
    const float4* za4 = (const float4*)z_atom + (size_t)c0 * (D_EMB / 4);
    #pragma unroll
    for (int it = 0; it < 16; ++it) {
        int idx = it * 64 + lane;
        int n = idx >> 5, c = idx & 31;
        tmp[it] = za4[n * (D_EMB / 4) + c];
    }

    // per-node hidden-bias gather (independent of LDS/MFMA; overlaps with loads)
    float4 hbf[2][2];
    #pragma unroll
    for (int nh = 0; nh < 2; ++nh) {
        int bn = __shfl(bv, l15 + 16 * nh);
        hbf[nh][0] = *(const float4*)&hb[(size_t)bn * HID + 4 * kc];
        hbf[nh][1] = *(const float4*)&hb[(size_t)bn * HID + 16 + 4 * kc];
    }

    // ---- phase B: convert + LDS write ----
    #pragma unroll
    for (int it = 0; it < 16; ++it) {
        int idx = it * 64 + lane;
        int n = idx >> 5, c = idx & 31;
        float4 v = tmp[it];
        unsigned lo = (unsigned)f2bf(v.x) | ((unsigned)f2bf(v.y) << 16);
        unsigned hi = (unsigned)f2bf(v.z) | ((unsigned)f2bf(v.w) << 16);
        *(uint2*)&zb[n][c * 4] = make_uint2(lo, hi);
    }

    // ---- logits: D[32j x 32n] via 2x2 tiles of mfma 16x16x32 ----
    f32x4 acc[2][2] = {{{0.f,0.f,0.f,0.f},{0.f,0.f,0.f,0.f}},
                       {{0.f,0.f,0.f,0.f},{0.f,0.f,0.f,0.f}}};
    #pragma unroll
    for (int kb = 0; kb < 4; ++kb) {
        short8 a0 = *(const short8*)&s_w1t[l15][kb * 32 + kc * 8];
        short8 a1 = *(const short8*)&s_w1t[16 + l15][kb * 32 + kc * 8];
        short8 q0 = *(const short8*)&zb[l15][kb * 32 + kc * 8];
        short8 q1 = *(const short8*)&zb[16 + l15][kb * 32 + kc * 8];
        acc[0][0] = __builtin_amdgcn_mfma_f32_16x16x32_bf16(a0, q0, acc[0][0], 0, 0, 0);
        acc[1][0] = __builtin_amdgcn_mfma_f32_16x16x32_bf16(a1, q0, acc[1][0], 0, 0, 0);
        acc[0][1] = __builtin_amdgcn_mfma_f32_16x16x32_bf16(a0, q1, acc[0][1], 0, 0, 0);
        acc[1][1] = __builtin_amdgcn_mfma_f32_16x16x32_bf16(a1, q1, acc[1][1], 0, 0, 0);
    }

    // ---- leaky + W2 + exp (node-local, no max needed) ----
    float pt[2];
    #pragma unroll
    for (int nh = 0; nh < 2; ++nh) {
        float part = 0.f;
        #pragma unroll
        for (int r = 0; r < 4; ++r) {
            float h = acc[0][nh][r] + (&hbf[nh][0].x)[r];
            h = h > 0.f ? h : 0.01f * h;
            part += h * w2v[0][r];
        }
        #pragma unroll
        for (int r = 0; r < 4; ++r) {
            float h = acc[1][nh][r] + (&hbf[nh][1].x)[r];
            h = h > 0.f ? h : 0.01f * h;
            part += h * w2v[1][r];
        }
        part += __shfl_xor(part, 16);
        part += __shfl_xor(part, 32);            // full logit in every lane
        pt[nh] = __expf(part + b2v);
    }

    // ---- pooling walk: lane owns dims 2*lane, 2*lane+1; flush on segment change ----
    const int* bp = batch + c0;                  // wave-uniform -> scalar loads
    float u0 = 0.f, u1 = 0.f, ss = 0.f;
    int cur = bp[0];
    #pragma unroll
    for (int n = 0; n < 32; ++n) {
        int bn = bp[n];
        if (bn != cur) {
            atomicAdd(&out_x[(size_t)cur * 256 + 128 + lane * 2], u0);
            atomicAdd(&out_x[(size_t)cur * 256 + 129 + lane * 2], u1);
            if (lane == 0) atomicAdd(&S[cur], ss);
            u0 = u1 = ss = 0.f;
            cur = bn;
        }
        float pn = (n < 16) ? __shfl(pt[0], n) : __shfl(pt[1], n - 16);
        unsigned zz = *(const unsigned*)&zb[n][lane * 2];
        u0 += pn * bf2f((unsigned short)(zz & 0xffffu));
        u1 += pn * bf2f((unsigned short)(zz >> 16));
        ss += pn;
    }
    atomicAdd(&out_x[(size_t)cur * 256 + 128 + lane * 2], u0);
    atomicAdd(&out_x[(size_t)cur * 256 + 129 + lane * 2], u1);
    if (lane == 0) atomicAdd(&S[cur], ss);
}

// ---------- K3: finalize: divide by S, copy z_mol ----------
__global__ __launch_bounds__(256) void fin_kernel(
    const float* __restrict__ z_mol, const float* __restrict__ S,
    float* __restrict__ out_x)
{
    int i = blockIdx.x * 256 + threadIdx.x;      // B*32 threads
    int g = i >> 5, q = i & 31;
    float4 zm = *(const float4*)&z_mol[(size_t)g * D_EMB + q * 4];
    *(float4*)&out_x[(size_t)g * 256 + q * 4] = zm;
    float inv = 1.f / (S[g] + 1e-16f);
    float4 u = *(float4*)&out_x[(size_t)g * 256 + 128 + q * 4];
    u.x *= inv; u.y *= inv; u.z *= inv; u.w *= inv;
    *(float4*)&out_x[(size_t)g * 256 + 128 + q * 4] = u;
}

// ---------- K4: edge concat ----------
__global__ __launch_bounds__(256) void edge_kernel(
    const float4* __restrict__ edge_attr4,
    const float4* __restrict__ state_emb4,
    const int*    __restrict__ state,
    const int*    __restrict__ eidx,
    const int*    __restrict__ batch,
    float4*       __restrict__ out4,
    int total)
{
    int tid = blockIdx.x * 256 + threadIdx.x;
    if (tid >= total) return;
    int e = tid / 24;
    int q = tid - e * 24;
    float4 v;
    if (q < 8) {
        v = edge_attr4[e * 8 + q];
    } else {
        int n = eidx[e];
        int b = batch[n];
        int s = state[b];
        v = state_emb4[s * 16 + (q - 8)];
    }
    out4[tid] = v;
}

extern "C" void kernel_launch(void* const* d_in, const int* in_sizes, int n_in,
                              void* d_out, int out_size, void* d_ws, size_t ws_size,
                              hipStream_t stream)
{
    const float* edge_attr = (const float*)d_in[0];
    const float* z_mol     = (const float*)d_in[1];
    const float* z_atom    = (const float*)d_in[2];
    const float* state_emb = (const float*)d_in[3];
    const float* W1        = (const float*)d_in[4];
    const float* b1        = (const float*)d_in[5];
    const float* W2        = (const float*)d_in[6];
    const float* b2        = (const float*)d_in[7];
    const int*   state     = (const int*)d_in[8];
    const int*   eidx      = (const int*)d_in[9];
    const int*   batch     = (const int*)d_in[10];

    float* out_x = (float*)d_out;
    float* out_e = out_x + (size_t)B_GRAPHS * 256;

    float* hbuf = (float*)d_ws;                                        // B*32 f32
    float* Sbuf = (float*)((char*)d_ws + (size_t)B_GRAPHS * HID * 4);  // B f32

    zero_kernel<<<(B_GRAPHS * 32) / 256, 256, 0, stream>>>(
        (float4*)out_x, (float4*)Sbuf);

    hb_kernel<<<B_GRAPHS / 8, 256, 0, stream>>>(state_emb, W1, b1, state, hbuf);

    graph_kernel<<<N_NODES / (WPB * 32), 256, 0, stream>>>(
        z_atom, W1, W2, b2, batch, hbuf, out_x, Sbuf);

    fin_kernel<<<(B_GRAPHS * 32) / 256, 256, 0, stream>>>(z_mol, Sbuf, out_x);

    const int total4 = E_EDGES * 24;
    edge_kernel<<<(total4 + 255) / 256, 256, 0, stream>>>(
        (const float4*)edge_attr, (const float4*)state_emb,
        state, eidx, batch, (float4*)out_e, total4);
}

// Round 6
// 252.811 us; speedup vs baseline: 1.0700x; 1.0700x over previous
//
#include <hip/hip_runtime.h>
#include <math.h>

#define B_GRAPHS 16384
#define N_NODES  524288
#define E_EDGES  1048576
#define D_EMB    128
#define D_STATE  64
#define HID      32
#define PADK     136     // bf16 elems/row -> 272B row stride (16B aligned)
#define WPB      4       // waves per block; each wave owns one 32-node window

typedef __attribute__((ext_vector_type(8))) short short8;
typedef __attribute__((ext_vector_type(4))) float f32x4;

__device__ __forceinline__ unsigned short f2bf(float f) {
    unsigned int u = __builtin_bit_cast(unsigned int, f);
    u += 0x7fffu + ((u >> 16) & 1u);
    return (unsigned short)(u >> 16);
}
__device__ __forceinline__ float bf2f(unsigned short s) {
    unsigned int u = ((unsigned int)s) << 16;
    return __builtin_bit_cast(float, u);
}

// ---------- K0: zero accumulator half of out_x rows + S (replay-safe) ----------
__global__ __launch_bounds__(256) void zero_kernel(float4* __restrict__ out4,
                                                   float4* __restrict__ S4)
{
    int i = blockIdx.x * 256 + threadIdx.x;          // B*32 threads
    int g = i >> 5, q = i & 31;
    out4[(size_t)g * 64 + 32 + q] = make_float4(0.f, 0.f, 0.f, 0.f);
    if (i < B_GRAPHS / 4) S4[i] = make_float4(0.f, 0.f, 0.f, 0.f);
}

// ---------- K1: hb[g][j] = b1[j] + state_emb[state[g]] @ W1[128:192,:] ----------
__global__ __launch_bounds__(256) void hb_kernel(
    const float* __restrict__ state_emb, const float* __restrict__ W1,
    const float* __restrict__ b1, const int* __restrict__ state,
    float* __restrict__ hb)
{
    int t = threadIdx.x;
    int j = t & 31;
    int g = blockIdx.x * 8 + (t >> 5);
    int st = state[g];
    const float* zs = state_emb + st * D_STATE;
    float acc = b1[j];
    #pragma unroll 8
    for (int k = 0; k < D_STATE; ++k)
        acc += zs[k] * W1[(D_EMB + k) * HID + j];
    hb[g * HID + j] = acc;
}

// ---------- K2: node-centric fused logits + exp + segment-flush pooling ----------
__global__ __launch_bounds__(256, 3) void graph_kernel(
    const float* __restrict__ z_atom,
    const float* __restrict__ W1,
    const float* __restrict__ W2,
    const float* __restrict__ b2,
    const int*   __restrict__ batch,
    const float* __restrict__ hb,
    float*       __restrict__ out_x,   // atomic accumulate into [g*256+128 .. +255]
    float*       __restrict__ S)       // atomic accumulate exp-sums
{
    __shared__ unsigned short s_w1t[HID][PADK];     // W1[0:128,:]^T bf16 [j][k]
    __shared__ unsigned short s_zb[WPB][32][PADK];  // per-wave z window bf16 [n][k]

    const int t    = threadIdx.x;
    const int lane = t & 63;
    const int w    = t >> 6;
    const int l15  = lane & 15;
    const int kc   = lane >> 4;        // 0..3

    // stage W1T once per block (W1 row-major [k][j], k<128)
    for (int i = t; i < D_EMB * HID; i += 256) {
        int k = i >> 5, j = i & 31;
        s_w1t[j][k] = f2bf(W1[i]);
    }
    __syncthreads();   // only block-wide barrier

    const float b2v = b2[0];
    float w2v[2][4];
    #pragma unroll
    for (int jh = 0; jh < 2; ++jh)
        #pragma unroll
        for (int r = 0; r < 4; ++r)
            w2v[jh][r] = W2[16 * jh + 4 * kc + r];

    unsigned short (*zb)[PADK] = s_zb[w];

    const int c0 = (blockIdx.x * WPB + w) * 32;     // dense window: 32 valid nodes
    int bv = 0;
    if (lane < 32) bv = batch[c0 + lane];

    // per-node hidden-bias gather (independent; overlaps with z loads below)
    float4 hbf[2][2];
    #pragma unroll
    for (int nh = 0; nh < 2; ++nh) {
        int bn = __shfl(bv, l15 + 16 * nh);
        hbf[nh][0] = *(const float4*)&hb[(size_t)bn * HID + 4 * kc];
        hbf[nh][1] = *(const float4*)&hb[(size_t)bn * HID + 16 + 4 * kc];
    }

    // ---- staging: two batches of 8 float4 in registers (32 VGPR each) ----
    const float4* za4 = (const float4*)z_atom + (size_t)c0 * (D_EMB / 4);
    #pragma unroll
    for (int half = 0; half < 2; ++half) {
        float4 tmp[8];
        #pragma unroll
        for (int it = 0; it < 8; ++it) {
            int idx = (half * 8 + it) * 64 + lane;
            int n = idx >> 5, c = idx & 31;
            tmp[it] = za4[n * (D_EMB / 4) + c];
        }
        #pragma unroll
        for (int it = 0; it < 8; ++it) {
            int idx = (half * 8 + it) * 64 + lane;
            int n = idx >> 5, c = idx & 31;
            float4 v = tmp[it];
            unsigned lo = (unsigned)f2bf(v.x) | ((unsigned)f2bf(v.y) << 16);
            unsigned hi = (unsigned)f2bf(v.z) | ((unsigned)f2bf(v.w) << 16);
            *(uint2*)&zb[n][c * 4] = make_uint2(lo, hi);
        }
    }

    // ---- logits: D[32j x 32n] via 2x2 tiles of mfma 16x16x32 ----
    f32x4 acc[2][2] = {{{0.f,0.f,0.f,0.f},{0.f,0.f,0.f,0.f}},
                       {{0.f,0.f,0.f,0.f},{0.f,0.f,0.f,0.f}}};
    #pragma unroll
    for (int kb = 0; kb < 4; ++kb) {
        short8 a0 = *(const short8*)&s_w1t[l15][kb * 32 + kc * 8];
        short8 a1 = *(const short8*)&s_w1t[16 + l15][kb * 32 + kc * 8];
        short8 q0 = *(const short8*)&zb[l15][kb * 32 + kc * 8];
        short8 q1 = *(const short8*)&zb[16 + l15][kb * 32 + kc * 8];
        acc[0][0] = __builtin_amdgcn_mfma_f32_16x16x32_bf16(a0, q0, acc[0][0], 0, 0, 0);
        acc[1][0] = __builtin_amdgcn_mfma_f32_16x16x32_bf16(a1, q0, acc[1][0], 0, 0, 0);
        acc[0][1] = __builtin_amdgcn_mfma_f32_16x16x32_bf16(a0, q1, acc[0][1], 0, 0, 0);
        acc[1][1] = __builtin_amdgcn_mfma_f32_16x16x32_bf16(a1, q1, acc[1][1], 0, 0, 0);
    }

    // ---- leaky + W2 + exp (node-local, no max needed) ----
    float pt[2];
    #pragma unroll
    for (int nh = 0; nh < 2; ++nh) {
        float part = 0.f;
        #pragma unroll
        for (int r = 0; r < 4; ++r) {
            float h = acc[0][nh][r] + (&hbf[nh][0].x)[r];
            h = h > 0.f ? h : 0.01f * h;
            part += h * w2v[0][r];
        }
        #pragma unroll
        for (int r = 0; r < 4; ++r) {
            float h = acc[1][nh][r] + (&hbf[nh][1].x)[r];
            h = h > 0.f ? h : 0.01f * h;
            part += h * w2v[1][r];
        }
        part += __shfl_xor(part, 16);
        part += __shfl_xor(part, 32);            // full logit in every lane
        pt[nh] = __expf(part + b2v);
    }

    // ---- pooling walk: lane owns dims 2*lane, 2*lane+1; flush on segment change ----
    // bn comes from the bv REGISTER (shfl broadcast) - no memory on the serial path.
    float u0 = 0.f, u1 = 0.f, ss = 0.f;
    int cur = __shfl(bv, 0);
    #pragma unroll
    for (int n = 0; n < 32; ++n) {
        int bn = __shfl(bv, n);
        if (bn != cur) {
            atomicAdd(&out_x[(size_t)cur * 256 + 128 + lane * 2], u0);
            atomicAdd(&out_x[(size_t)cur * 256 + 129 + lane * 2], u1);
            if (lane == 0) atomicAdd(&S[cur], ss);
            u0 = u1 = ss = 0.f;
            cur = bn;
        }
        float pn = (n < 16) ? __shfl(pt[0], n) : __shfl(pt[1], n - 16);
        unsigned zz = *(const unsigned*)&zb[n][lane * 2];
        u0 += pn * bf2f((unsigned short)(zz & 0xffffu));
        u1 += pn * bf2f((unsigned short)(zz >> 16));
        ss += pn;
    }
    atomicAdd(&out_x[(size_t)cur * 256 + 128 + lane * 2], u0);
    atomicAdd(&out_x[(size_t)cur * 256 + 129 + lane * 2], u1);
    if (lane == 0) atomicAdd(&S[cur], ss);
}

// ---------- K3: finalize: divide by S, copy z_mol ----------
__global__ __launch_bounds__(256) void fin_kernel(
    const float* __restrict__ z_mol, const float* __restrict__ S,
    float* __restrict__ out_x)
{
    int i = blockIdx.x * 256 + threadIdx.x;      // B*32 threads
    int g = i >> 5, q = i & 31;
    float4 zm = *(const float4*)&z_mol[(size_t)g * D_EMB + q * 4];
    *(float4*)&out_x[(size_t)g * 256 + q * 4] = zm;
    float inv = 1.f / (S[g] + 1e-16f);
    float4 u = *(float4*)&out_x[(size_t)g * 256 + 128 + q * 4];
    u.x *= inv; u.y *= inv; u.z *= inv; u.w *= inv;
    *(float4*)&out_x[(size_t)g * 256 + 128 + q * 4] = u;
}

// ---------- K4: edge concat ----------
__global__ __launch_bounds__(256) void edge_kernel(
    const float4* __restrict__ edge_attr4,
    const float4* __restrict__ state_emb4,
    const int*    __restrict__ state,
    const int*    __restrict__ eidx,
    const int*    __restrict__ batch,
    float4*       __restrict__ out4,
    int total)
{
    int tid = blockIdx.x * 256 + threadIdx.x;
    if (tid >= total) return;
    int e = tid / 24;
    int q = tid - e * 24;
    float4 v;
    if (q < 8) {
        v = edge_attr4[e * 8 + q];
    } else {
        int n = eidx[e];
        int b = batch[n];
        int s = state[b];
        v = state_emb4[s * 16 + (q - 8)];
    }
    out4[tid] = v;
}

extern "C" void kernel_launch(void* const* d_in, const int* in_sizes, int n_in,
                              void* d_out, int out_size, void* d_ws, size_t ws_size,
                              hipStream_t stream)
{
    const float* edge_attr = (const float*)d_in[0];
    const float* z_mol     = (const float*)d_in[1];
    const float* z_atom    = (const float*)d_in[2];
    const float* state_emb = (const float*)d_in[3];
    const float* W1        = (const float*)d_in[4];
    const float* b1        = (const float*)d_in[5];
    const float* W2        = (const float*)d_in[6];
    const float* b2        = (const float*)d_in[7];
    const int*   state     = (const int*)d_in[8];
    const int*   eidx      = (const int*)d_in[9];
    const int*   batch     = (const int*)d_in[10];

    float* out_x = (float*)d_out;
    float* out_e = out_x + (size_t)B_GRAPHS * 256;

    float* hbuf = (float*)d_ws;                                        // B*32 f32
    float* Sbuf = (float*)((char*)d_ws + (size_t)B_GRAPHS * HID * 4);  // B f32

    zero_kernel<<<(B_GRAPHS * 32) / 256, 256, 0, stream>>>(
        (float4*)out_x, (float4*)Sbuf);

    hb_kernel<<<B_GRAPHS / 8, 256, 0, stream>>>(state_emb, W1, b1, state, hbuf);

    graph_kernel<<<N_NODES / (WPB * 32), 256, 0, stream>>>(
        z_atom, W1, W2, b2, batch, hbuf, out_x, Sbuf);

    fin_kernel<<<(B_GRAPHS * 32) / 256, 256, 0, stream>>>(z_mol, Sbuf, out_x);

    const int total4 = E_EDGES * 24;
    edge_kernel<<<(total4 + 255) / 256, 256, 0, stream>>>(
        (const float4*)edge_attr, (const float4*)state_emb,
        state, eidx, batch, (float4*)out_e, total4);
}